// Round 7
// baseline (700.546 us; speedup 1.0000x reference)
//
#include <hip/hip_runtime.h>
#include <math.h>

// Problem constants
#define A_N   8400
#define BS    32
#define NGT   64
#define NC    80
#define TK    13
#define EPSF  1e-9f
#define CAP   1024          // dense per-(b,gt) candidate list capacity
#define JG    16            // gts per k_cand block (64 split in 4 groups)
#define NJG   4
#define NTILE 33            // ceil(8400/256)
#define PCAP  64            // LDS pool capacity per (block, gt)
#define NCAND (BS * NTILE * NJG)   // 4224 k_cand blocks
#define NBLK_TAIL 768       // k_tail grid: <= 1024 co-resident @ launch_bounds(256,4)

typedef float nt4 __attribute__((ext_vector_type(4)));   // native vec for nontemporal store

// Output layout (floats), concatenated in reference return order
#define OFF_LB 0
#define OFF_BB (BS * A_N)
#define OFF_SC (OFF_BB + BS * A_N * 4)
#define OFF_FG (OFF_SC + BS * A_N * NC)

// Workspace layout (byte offsets, all 256-aligned)
#define WS_FLAG   0            // flag @0, bar[2] @16
#define WS_CNT    256
#define WS_MINJ   (WS_CNT   + BS * A_N * 4)
#define WS_INFO   (WS_MINJ  + BS * A_N * 4)
#define WS_ALIGN  (WS_INFO  + BS * A_N * 4)
#define WS_POSA   (WS_ALIGN + BS * A_N * 4)
#define WS_POSO   (WS_POSA  + BS * NGT * 4)
#define WS_CNT2   (WS_POSO  + BS * NGT * 4)
#define WS_CAND   (WS_CNT2  + BS * NGT * 4)
// cand: 2048 * CAP * 8 = 16.78 MB ; total ~= 21.1 MB

__device__ __forceinline__ float iou_f(float g0, float g1, float g2, float g3,
                                       float p0, float p1, float p2, float p3) {
    float ltx = fmaxf(g0, p0), lty = fmaxf(g1, p1);
    float rbx = fminf(g2, p2), rby = fminf(g3, p3);
    float ov  = fmaxf(rbx - ltx, 0.f) * fmaxf(rby - lty, 0.f);
    float a1  = fmaxf(g2 - g0, 0.f) * fmaxf(g3 - g1, 0.f);
    float a2  = fmaxf(p2 - p0, 0.f) * fmaxf(p3 - p1, 0.f);
    return ov / (a1 + a2 - ov + EPSF);
}

__device__ __forceinline__ int get_gl(const int* g, int flag64, int i) {
    return flag64 ? g[2 * i] : g[i];
}

__device__ __forceinline__ unsigned long long shfl_xor_u64(unsigned long long x, int m) {
    int lo = __shfl_xor((int)(unsigned int)(x & 0xFFFFFFFFull), m, 64);
    int hi = __shfl_xor((int)(unsigned int)(x >> 32), m, 64);
    return ((unsigned long long)(unsigned int)hi << 32) | (unsigned int)lo;
}

// Software grid barrier (one-shot counter per use; zeroed in k_init).
// Device-scope atomics + fences per G16; co-residency by capacity arithmetic.
__device__ __forceinline__ void gbar(int* ctr, int nblk) {
    __syncthreads();
    __threadfence();                       // release
    if (threadIdx.x == 0) {
        __hip_atomic_fetch_add(ctr, 1, __ATOMIC_ACQ_REL, __HIP_MEMORY_SCOPE_AGENT);
        while (__hip_atomic_load(ctr, __ATOMIC_ACQUIRE, __HIP_MEMORY_SCOPE_AGENT) < nblk)
            __builtin_amdgcn_s_sleep(1);
    }
    __syncthreads();
    __threadfence();                       // acquire / L1 invalidate
}

// ---------------- Kernel 0: init small counters + detect gt_labels stride ----
__global__ __launch_bounds__(256) void k_init(unsigned int* posA, unsigned int* posO,
                                              int* cnt2, int* flag, int* bar,
                                              const int* gl_raw) {
    int i = blockIdx.x * 256 + threadIdx.x;
    if (i < BS * NGT) { posA[i] = 0u; posO[i] = 0u; cnt2[i] = 0; }
    if (i == 1 || i == 2) bar[i - 1] = 0;
    if (i == 0) {
        int f = 1;
        for (int k = 0; k < 64; k++) {
            if (gl_raw[2 * k + 1] != 0) { f = 0; break; }
        }
        *flag = f;
    }
}

// ---------------- Kernel 1: dense in-box sweep -> candidate lists ------------
// Absorbed zero-fills run POST-barrier (drain at kernel retire only, overlap
// other blocks' latency-bound hit loops).
__global__ __launch_bounds__(256) void k_cand(
    const float* __restrict__ pd_scores, const float* __restrict__ pd_bboxes,
    const float* __restrict__ anc, const int* __restrict__ gl_raw,
    const float* __restrict__ gt_bboxes, const float* __restrict__ mask_gt,
    const int* __restrict__ flag,
    int* __restrict__ cnt2, unsigned long long* __restrict__ cand,
    int* __restrict__ cnt, int* __restrict__ minj, float* __restrict__ out) {
    __shared__ float4 sgt[JG];
    __shared__ int    slbl[JG];
    __shared__ int    smask[JG];
    __shared__ int    cnt_lds[JG];
    __shared__ int    base_lds[JG];
    __shared__ unsigned long long pool[JG][PCAP];

    int bid  = blockIdx.x;
    int b    = bid / (NTILE * NJG);
    int rem  = bid % (NTILE * NJG);
    int tile = rem / NJG;
    int jg   = rem % NJG;
    int tid  = threadIdx.x;
    int a    = tile * 256 + tid;
    int jbase = b * NGT + jg * JG;

    if (tid < JG) {
        sgt[tid]   = ((const float4*)gt_bboxes)[jbase + tid];
        slbl[tid]  = get_gl(gl_raw, *flag, jbase + tid);
        smask[tid] = (mask_gt[jbase + tid] != 0.f);
        cnt_lds[tid] = 0;
    }
    __syncthreads();

    bool act = (a < A_N);
    float2 an = make_float2(0.f, 0.f);
    float4 p  = make_float4(0.f, 0.f, 0.f, 0.f);
    const float* sc = pd_scores;
    if (act) {
        an = ((const float2*)anc)[a];
        p  = ((const float4*)pd_bboxes)[(size_t)b * A_N + a];
        sc = pd_scores + (size_t)b * A_N * NC + (size_t)a * NC;
    }

    // Phase A: hit detection + LDS append
    for (int j = 0; j < JG; j++) {
        if (!smask[j]) continue;                       // block-uniform
        if (!act) continue;
        float4 g = sgt[j];
        float d = fminf(fminf(an.x - g.x, an.y - g.y),
                        fminf(g.z - an.x, g.w - an.y));
        if (d > EPSF) {
            float iou = iou_f(g.x, g.y, g.z, g.w, p.x, p.y, p.z, p.w);
            float m = 0.f;
            if (iou > 0.f) {
                float s = sc[slbl[j]];
                m = s * powf(iou, 6.0f);               // identical op order (absmax 0.0)
            }
            unsigned long long key =
                ((unsigned long long)__float_as_uint(m) << 32) |
                (unsigned int)(~(unsigned int)a);      // (metric desc, anchor asc) under max
            int slot = atomicAdd(&cnt_lds[j], 1);      // LDS atomic
            if (slot < PCAP) {
                pool[j][slot] = key;
            } else {                                   // rare overflow: direct global
                int gs = atomicAdd(&cnt2[jbase + j], 1);
                if (gs < CAP) cand[(size_t)(jbase + j) * CAP + gs] = key;
            }
        }
    }
    __syncthreads();

    // Phase B: one global reservation per gt, issued in parallel
    if (tid < JG) {
        int c = min(cnt_lds[tid], PCAP);
        int bas = 0;
        if (c > 0) bas = atomicAdd(&cnt2[jbase + tid], c);
        base_lds[tid] = bas;
    }
    __syncthreads();

    // Phase C: flush LDS pools to global
    for (int j = 0; j < JG; j++) {
        int c = min(cnt_lds[j], PCAP);
        int bas = base_lds[j];
        for (int t = tid; t < c; t += 256) {
            int dst = bas + t;
            if (dst < CAP) cand[(size_t)(jbase + j) * CAP + dst] = pool[j][t];
        }
    }

    // Phase D (post-barrier): absorbed zero-fills; drain at kernel retire only
    {
        int gth = bid * 256 + tid;
        const int GS = NCAND * 256;
        nt4* scz = (nt4*)(out + OFF_SC);
        for (int t = gth; t < BS * A_N * (NC / 4); t += GS)
            __builtin_nontemporal_store((nt4)(0.f), &scz[t]);
        for (int t = gth; t < BS * A_N; t += GS) {
            cnt[t] = 0; minj[t] = 1 << 30;
        }
    }
}

// ---------------- pick helper: per-(b,gt) wave top-13 + scatter --------------
template <int NT>
__device__ __forceinline__ void pick_body(
    int lane, int b, int j, int n, const unsigned long long* __restrict__ L,
    int* __restrict__ cnt, int* __restrict__ minj) {
    unsigned long long k0[NT];
    #pragma unroll
    for (int t = 0; t < NT; t++) {
        int i = t * 64 + lane;
        k0[t] = (i < n) ? L[i] : 0ULL;                 // 0 = empty (real keys nonzero)
    }

    unsigned int wanchor[TK];
    int P = 0;
    #pragma unroll
    for (int r = 0; r < TK; r++) {
        unsigned long long best = 0;
        #pragma unroll
        for (int t = 0; t < NT; t++) best = (k0[t] > best) ? k0[t] : best;
        for (int s = 1; s < 64; s <<= 1) {
            unsigned long long o = shfl_xor_u64(best, s);
            if (o > best) best = o;
        }
        if (!(best >> 32)) break;                      // out of positive metrics
        unsigned int aw = ~(unsigned int)(best & 0xFFFFFFFFull);
        wanchor[r] = aw;
        if (lane == 0) {
            atomicAdd(&cnt[b * A_N + (int)aw], 1);
            atomicMin(&minj[b * A_N + (int)aw], j);
        }
        #pragma unroll
        for (int t = 0; t < NT; t++) if (k0[t] == best) k0[t] = 0;
        P++;
    }

    // Fillers: top_k back-fills (13-P) lowest-index zero-metric anchors of the
    // full array; only in-box ones (all present as zero-metric candidates)
    // survive mask_in_gts. a is a filler iff a - |{positive winners < a}| < 13-P.
    if (P < TK) {
        int K = TK - P;
        #pragma unroll
        for (int t = 0; t < NT; t++) {
            unsigned long long key = k0[t];
            if (key != 0 && !(key >> 32)) {
                unsigned int a0 = ~(unsigned int)(key & 0xFFFFFFFFull);
                int off = 0;
                #pragma unroll
                for (int r = 0; r < TK; r++)
                    if (r < P && wanchor[r] < a0) off++;
                if ((int)a0 < K + off) {
                    atomicAdd(&cnt[b * A_N + (int)a0], 1);
                    atomicMin(&minj[b * A_N + (int)a0], j);
                }
            }
        }
    }
}

// ---------------- Kernel 2 (fused): pick -> [gbar] -> assign -> [gbar] -> norm
__global__ __launch_bounds__(256, 4) void k_tail(
    const float* __restrict__ pd_scores, const float* __restrict__ pd_bboxes,
    const float* __restrict__ gt_bboxes, const int* __restrict__ gl_raw,
    const int* __restrict__ flag,
    const int* __restrict__ cnt2, const unsigned long long* __restrict__ cand,
    int* __restrict__ cnt, int* __restrict__ minj,
    int* __restrict__ info, float* __restrict__ alignArr,
    unsigned int* posA, unsigned int* posO,
    int* __restrict__ bar, float* __restrict__ out) {
    int tid  = threadIdx.x;
    int lane = tid & 63;
    int f64  = *flag;

    // ---- Phase 1: top-13 pick, grid-stride over 2048 (b,gt) waves ----
    for (int bj = blockIdx.x * 4 + (tid >> 6); bj < BS * NGT; bj += NBLK_TAIL * 4) {
        int n = min(cnt2[bj], CAP);
        if (n == 0) continue;                          // wave-uniform
        int b = bj >> 6, j = bj & 63;
        const unsigned long long* L = cand + (size_t)bj * CAP;
        if (n <= 128)      pick_body<2>(lane, b, j, n, L, cnt, minj);
        else if (n <= 320) pick_body<5>(lane, b, j, n, L, cnt, minj);
        else               pick_body<16>(lane, b, j, n, L, cnt, minj);
    }

    gbar(&bar[0], NBLK_TAIL);

    // ---- Phase 2: per-anchor assignment ----
    for (int i = blockIdx.x * 256 + tid; i < BS * A_N; i += NBLK_TAIL * 256) {
        int b = i / A_N;
        int c = cnt[i];

        float4 p = ((const float4*)pd_bboxes)[i];
        int jstar = 0;
        if (c == 1) {
            jstar = minj[i];
        } else if (c > 1) {
            float bv = -1.f; int bj_ = 0;
            const float4* gb = (const float4*)(gt_bboxes + (size_t)b * NGT * 4);
            for (int j = 0; j < NGT; j++) {
                float4 g = gb[j];
                float ov = iou_f(g.x, g.y, g.z, g.w, p.x, p.y, p.z, p.w);
                if (ov > bv) { bv = ov; bj_ = j; }
            }
            jstar = bj_;
        }

        int lbl = get_gl(gl_raw, f64, b * NGT + jstar);
        if (lbl < 0) lbl = 0;

        out[OFF_LB + i] = (float)lbl;
        float4 g = ((const float4*)gt_bboxes)[b * NGT + jstar];
        ((float4*)(out + OFF_BB))[i] = g;

        int fg = (c > 0) ? 1 : 0;
        out[OFF_FG + i] = (float)fg;

        float al = 0.f;
        if (fg) {
            float ov = iou_f(g.x, g.y, g.z, g.w, p.x, p.y, p.z, p.w);
            float s  = pd_scores[(size_t)i * NC + lbl];
            al = s * powf(ov, 6.0f);
            atomicMax((int*)&posA[b * NGT + jstar], __float_as_int(al));
            atomicMax((int*)&posO[b * NGT + jstar], __float_as_int(ov));
        }
        alignArr[i] = al;
        info[i] = jstar | (lbl << 8) | (fg << 16);
    }

    gbar(&bar[1], NBLK_TAIL);

    // ---- Phase 3: sparse norm scatter (fg anchors only) ----
    for (int i = blockIdx.x * 256 + tid; i < BS * A_N; i += NBLK_TAIL * 256) {
        int inf = info[i];
        if (!(inf & (1 << 16))) continue;  // background: zero-fill done in k_cand
        int jstar = inf & 255;
        int lbl   = (inf >> 8) & 255;
        int b = i / A_N;
        float pa = __int_as_float((int)posA[b * NGT + jstar]);
        float po = __int_as_float((int)posO[b * NGT + jstar]);
        out[OFF_SC + (size_t)i * NC + lbl] = alignArr[i] * po / (pa + EPSF);
    }
}

extern "C" void kernel_launch(void* const* d_in, const int* in_sizes, int n_in,
                              void* d_out, int out_size, void* d_ws, size_t ws_size,
                              hipStream_t stream) {
    const float* pd_scores = (const float*)d_in[0];
    const float* pd_bboxes = (const float*)d_in[1];
    const float* anc       = (const float*)d_in[2];
    const int*   gl_raw    = (const int*)d_in[3];
    const float* gt_bboxes = (const float*)d_in[4];
    const float* mask_gt   = (const float*)d_in[5];
    float* out = (float*)d_out;

    char* ws = (char*)d_ws;
    int*                flag     = (int*)(ws + WS_FLAG);
    int*                bar      = (int*)(ws + WS_FLAG + 16);
    int*                cnt      = (int*)(ws + WS_CNT);
    int*                minj     = (int*)(ws + WS_MINJ);
    int*                info     = (int*)(ws + WS_INFO);
    float*              alignArr = (float*)(ws + WS_ALIGN);
    unsigned int*       posA     = (unsigned int*)(ws + WS_POSA);
    unsigned int*       posO     = (unsigned int*)(ws + WS_POSO);
    int*                cnt2     = (int*)(ws + WS_CNT2);
    unsigned long long* cand     = (unsigned long long*)(ws + WS_CAND);

    k_init<<<8, 256, 0, stream>>>(posA, posO, cnt2, flag, bar, gl_raw);
    k_cand<<<NCAND, 256, 0, stream>>>(pd_scores, pd_bboxes, anc, gl_raw,
                                      gt_bboxes, mask_gt, flag, cnt2, cand,
                                      cnt, minj, out);
    k_tail<<<NBLK_TAIL, 256, 0, stream>>>(pd_scores, pd_bboxes, gt_bboxes, gl_raw,
                                          flag, cnt2, cand, cnt, minj,
                                          info, alignArr, posA, posO, bar, out);
}

// Round 8
// 209.688 us; speedup vs baseline: 3.3409x; 3.3409x over previous
//
#include <hip/hip_runtime.h>
#include <math.h>

// Problem constants
#define A_N   8400
#define BS    32
#define NGT   64
#define NC    80
#define TK    13
#define EPSF  1e-9f
#define CAP   1024          // dense per-(b,gt) candidate list capacity
#define JG    16            // gts per k_cand block (64 split in 4 groups)
#define NJG   4
#define NTILE 33            // ceil(8400/256)
#define PCAP  64            // LDS pool capacity per (block, gt)
#define NCAND (BS * NTILE * NJG)   // 4224 k_cand blocks

typedef float nt4 __attribute__((ext_vector_type(4)));   // native vec for nontemporal store

// Output layout (floats), concatenated in reference return order
#define OFF_LB 0
#define OFF_BB (BS * A_N)
#define OFF_SC (OFF_BB + BS * A_N * 4)
#define OFF_FG (OFF_SC + BS * A_N * NC)

// Workspace layout (byte offsets, all 256-aligned)
#define WS_FLAG   0
#define WS_CNT    256
#define WS_MINJ   (WS_CNT   + BS * A_N * 4)
#define WS_INFO   (WS_MINJ  + BS * A_N * 4)
#define WS_ALIGN  (WS_INFO  + BS * A_N * 4)
#define WS_POSA   (WS_ALIGN + BS * A_N * 4)
#define WS_POSO   (WS_POSA  + BS * NGT * 4)
#define WS_CNT2   (WS_POSO  + BS * NGT * 4)
#define WS_CAND   (WS_CNT2  + BS * NGT * 4)
// cand: 2048 * CAP * 8 = 16.78 MB ; total ~= 21.1 MB

// NOTE (R7 lesson): software grid barriers (device-scope atomic spin) cost
// ~250 us EACH on MI355X — 768 blocks spinning on one cacheline starve the
// workers. Separate kernel launches (~2 us gap) are 100x cheaper. Never fuse
// dependent grid-wide phases with a spin barrier here.

__device__ __forceinline__ float iou_f(float g0, float g1, float g2, float g3,
                                       float p0, float p1, float p2, float p3) {
    float ltx = fmaxf(g0, p0), lty = fmaxf(g1, p1);
    float rbx = fminf(g2, p2), rby = fminf(g3, p3);
    float ov  = fmaxf(rbx - ltx, 0.f) * fmaxf(rby - lty, 0.f);
    float a1  = fmaxf(g2 - g0, 0.f) * fmaxf(g3 - g1, 0.f);
    float a2  = fmaxf(p2 - p0, 0.f) * fmaxf(p3 - p1, 0.f);
    return ov / (a1 + a2 - ov + EPSF);
}

__device__ __forceinline__ int get_gl(const int* g, int flag64, int i) {
    return flag64 ? g[2 * i] : g[i];
}

__device__ __forceinline__ unsigned long long shfl_xor_u64(unsigned long long x, int m) {
    int lo = __shfl_xor((int)(unsigned int)(x & 0xFFFFFFFFull), m, 64);
    int hi = __shfl_xor((int)(unsigned int)(x >> 32), m, 64);
    return ((unsigned long long)(unsigned int)hi << 32) | (unsigned int)lo;
}

// ---------------- Kernel 0: init small counters + detect gt_labels stride ----
__global__ __launch_bounds__(256) void k_init(unsigned int* posA, unsigned int* posO,
                                              int* cnt2, int* flag, const int* gl_raw) {
    int i = blockIdx.x * 256 + threadIdx.x;
    if (i < BS * NGT) { posA[i] = 0u; posO[i] = 0u; cnt2[i] = 0; }
    if (i == 0) {
        int f = 1;
        for (int k = 0; k < 64; k++) {
            if (gl_raw[2 * k + 1] != 0) { f = 0; break; }
        }
        *flag = f;
    }
}

// ---------------- Kernel 1: dense in-box sweep -> candidate lists ------------
// Absorbed zero-fills run POST-barrier (drain at kernel retire only, overlap
// other blocks' latency-bound hit loops).
__global__ __launch_bounds__(256) void k_cand(
    const float* __restrict__ pd_scores, const float* __restrict__ pd_bboxes,
    const float* __restrict__ anc, const int* __restrict__ gl_raw,
    const float* __restrict__ gt_bboxes, const float* __restrict__ mask_gt,
    const int* __restrict__ flag,
    int* __restrict__ cnt2, unsigned long long* __restrict__ cand,
    int* __restrict__ cnt, int* __restrict__ minj, float* __restrict__ out) {
    __shared__ float4 sgt[JG];
    __shared__ int    slbl[JG];
    __shared__ int    smask[JG];
    __shared__ int    cnt_lds[JG];
    __shared__ int    base_lds[JG];
    __shared__ unsigned long long pool[JG][PCAP];

    int bid  = blockIdx.x;
    int b    = bid / (NTILE * NJG);
    int rem  = bid % (NTILE * NJG);
    int tile = rem / NJG;
    int jg   = rem % NJG;
    int tid  = threadIdx.x;
    int a    = tile * 256 + tid;
    int jbase = b * NGT + jg * JG;

    if (tid < JG) {
        sgt[tid]   = ((const float4*)gt_bboxes)[jbase + tid];
        slbl[tid]  = get_gl(gl_raw, *flag, jbase + tid);
        smask[tid] = (mask_gt[jbase + tid] != 0.f);
        cnt_lds[tid] = 0;
    }
    __syncthreads();

    bool act = (a < A_N);
    float2 an = make_float2(0.f, 0.f);
    float4 p  = make_float4(0.f, 0.f, 0.f, 0.f);
    const float* sc = pd_scores;
    if (act) {
        an = ((const float2*)anc)[a];
        p  = ((const float4*)pd_bboxes)[(size_t)b * A_N + a];
        sc = pd_scores + (size_t)b * A_N * NC + (size_t)a * NC;
    }

    // Phase A: hit detection + LDS append
    for (int j = 0; j < JG; j++) {
        if (!smask[j]) continue;                       // block-uniform
        if (!act) continue;
        float4 g = sgt[j];
        float d = fminf(fminf(an.x - g.x, an.y - g.y),
                        fminf(g.z - an.x, g.w - an.y));
        if (d > EPSF) {
            float iou = iou_f(g.x, g.y, g.z, g.w, p.x, p.y, p.z, p.w);
            float m = 0.f;
            if (iou > 0.f) {
                float s = sc[slbl[j]];
                m = s * powf(iou, 6.0f);               // identical op order (absmax 0.0)
            }
            unsigned long long key =
                ((unsigned long long)__float_as_uint(m) << 32) |
                (unsigned int)(~(unsigned int)a);      // (metric desc, anchor asc) under max
            int slot = atomicAdd(&cnt_lds[j], 1);      // LDS atomic
            if (slot < PCAP) {
                pool[j][slot] = key;
            } else {                                   // rare overflow: direct global
                int gs = atomicAdd(&cnt2[jbase + j], 1);
                if (gs < CAP) cand[(size_t)(jbase + j) * CAP + gs] = key;
            }
        }
    }
    __syncthreads();

    // Phase B: one global reservation per gt, issued in parallel
    if (tid < JG) {
        int c = min(cnt_lds[tid], PCAP);
        int bas = 0;
        if (c > 0) bas = atomicAdd(&cnt2[jbase + tid], c);
        base_lds[tid] = bas;
    }
    __syncthreads();

    // Phase C: flush LDS pools to global
    for (int j = 0; j < JG; j++) {
        int c = min(cnt_lds[j], PCAP);
        int bas = base_lds[j];
        for (int t = tid; t < c; t += 256) {
            int dst = bas + t;
            if (dst < CAP) cand[(size_t)(jbase + j) * CAP + dst] = pool[j][t];
        }
    }

    // Phase D (post-barrier): absorbed zero-fills; drain at kernel retire only
    {
        int gth = bid * 256 + tid;
        const int GS = NCAND * 256;
        nt4* scz = (nt4*)(out + OFF_SC);
        for (int t = gth; t < BS * A_N * (NC / 4); t += GS)
            __builtin_nontemporal_store((nt4)(0.f), &scz[t]);
        for (int t = gth; t < BS * A_N; t += GS) {
            cnt[t] = 0; minj[t] = 1 << 30;
        }
    }
}

// ---------------- Kernel 2: per-(b,gt) wave top-13 + scatter -----------------
template <int NT>
__device__ __forceinline__ void pick_body(
    int lane, int b, int j, int n, const unsigned long long* __restrict__ L,
    int* __restrict__ cnt, int* __restrict__ minj) {
    unsigned long long k0[NT];
    #pragma unroll
    for (int t = 0; t < NT; t++) {
        int i = t * 64 + lane;
        k0[t] = (i < n) ? L[i] : 0ULL;                 // 0 = empty (real keys nonzero)
    }

    unsigned int wanchor[TK];
    int P = 0;
    #pragma unroll
    for (int r = 0; r < TK; r++) {
        unsigned long long best = 0;
        #pragma unroll
        for (int t = 0; t < NT; t++) best = (k0[t] > best) ? k0[t] : best;
        for (int s = 1; s < 64; s <<= 1) {
            unsigned long long o = shfl_xor_u64(best, s);
            if (o > best) best = o;
        }
        if (!(best >> 32)) break;                      // out of positive metrics
        unsigned int aw = ~(unsigned int)(best & 0xFFFFFFFFull);
        wanchor[r] = aw;
        if (lane == 0) {
            atomicAdd(&cnt[b * A_N + (int)aw], 1);
            atomicMin(&minj[b * A_N + (int)aw], j);
        }
        #pragma unroll
        for (int t = 0; t < NT; t++) if (k0[t] == best) k0[t] = 0;
        P++;
    }

    // Fillers: top_k back-fills (13-P) lowest-index zero-metric anchors of the
    // full array; only in-box ones (all present as zero-metric candidates)
    // survive mask_in_gts. a is a filler iff a - |{positive winners < a}| < 13-P.
    if (P < TK) {
        int K = TK - P;
        #pragma unroll
        for (int t = 0; t < NT; t++) {
            unsigned long long key = k0[t];
            if (key != 0 && !(key >> 32)) {
                unsigned int a0 = ~(unsigned int)(key & 0xFFFFFFFFull);
                int off = 0;
                #pragma unroll
                for (int r = 0; r < TK; r++)
                    if (r < P && wanchor[r] < a0) off++;
                if ((int)a0 < K + off) {
                    atomicAdd(&cnt[b * A_N + (int)a0], 1);
                    atomicMin(&minj[b * A_N + (int)a0], j);
                }
            }
        }
    }
}

__global__ __launch_bounds__(256) void k_pick(
    const int* __restrict__ cnt2, const unsigned long long* __restrict__ cand,
    int* __restrict__ cnt, int* __restrict__ minj) {
    int lane = threadIdx.x & 63;
    int wave = threadIdx.x >> 6;
    int bj = blockIdx.x * 4 + wave;
    int b = bj >> 6, j = bj & 63;

    int n = min(cnt2[bj], CAP);
    if (n == 0) return;                                // wave-uniform
    const unsigned long long* L = cand + (size_t)bj * CAP;

    // wave-uniform tier dispatch: compile-time bounds keep k0[] in registers
    if (n <= 128)      pick_body<2>(lane, b, j, n, L, cnt, minj);
    else if (n <= 320) pick_body<5>(lane, b, j, n, L, cnt, minj);
    else               pick_body<16>(lane, b, j, n, L, cnt, minj);
}

// ---------------- Kernel 3: per-anchor assignment + labels/bboxes/fg ---------
__global__ __launch_bounds__(256) void k_assign(
    const float* __restrict__ pd_scores, const float* __restrict__ pd_bboxes,
    const float* __restrict__ gt_bboxes, const int* __restrict__ gl_raw,
    const int* __restrict__ flag,
    const int* __restrict__ cnt, const int* __restrict__ minj,
    int* __restrict__ info, float* __restrict__ alignArr,
    unsigned int* posA, unsigned int* posO, float* __restrict__ out) {
    int i = blockIdx.x * 256 + threadIdx.x;
    if (i >= BS * A_N) return;
    int b = i / A_N;
    int c = cnt[i];
    int f64 = *flag;

    float4 p = ((const float4*)pd_bboxes)[i];
    int jstar = 0;
    if (c == 1) {
        jstar = minj[i];
    } else if (c > 1) {
        float bv = -1.f; int bj_ = 0;
        const float4* gb = (const float4*)(gt_bboxes + (size_t)b * NGT * 4);
        for (int j = 0; j < NGT; j++) {
            float4 g = gb[j];
            float ov = iou_f(g.x, g.y, g.z, g.w, p.x, p.y, p.z, p.w);
            if (ov > bv) { bv = ov; bj_ = j; }
        }
        jstar = bj_;
    }

    int lbl = get_gl(gl_raw, f64, b * NGT + jstar);
    if (lbl < 0) lbl = 0;

    out[OFF_LB + i] = (float)lbl;
    float4 g = ((const float4*)gt_bboxes)[b * NGT + jstar];
    ((float4*)(out + OFF_BB))[i] = g;

    int fg = (c > 0) ? 1 : 0;
    out[OFF_FG + i] = (float)fg;

    float al = 0.f;
    if (fg) {
        float ov = iou_f(g.x, g.y, g.z, g.w, p.x, p.y, p.z, p.w);
        float s  = pd_scores[(size_t)i * NC + lbl];
        al = s * powf(ov, 6.0f);
        atomicMax((int*)&posA[b * NGT + jstar], __float_as_int(al));
        atomicMax((int*)&posO[b * NGT + jstar], __float_as_int(ov));
    }
    alignArr[i] = al;
    info[i] = jstar | (lbl << 8) | (fg << 16);
}

// ---------------- Kernel 4: sparse norm scatter (fg anchors only) ------------
__global__ __launch_bounds__(256) void k_norm(
    const int* __restrict__ info, const float* __restrict__ alignArr,
    const unsigned int* __restrict__ posA, const unsigned int* __restrict__ posO,
    float* __restrict__ out) {
    int i = blockIdx.x * 256 + threadIdx.x;
    if (i >= BS * A_N) return;
    int inf = info[i];
    if (!(inf & (1 << 16))) return;        // background: zero-fill already done in k_cand
    int jstar = inf & 255;
    int lbl   = (inf >> 8) & 255;
    int b = i / A_N;
    float pa = __int_as_float((int)posA[b * NGT + jstar]);
    float po = __int_as_float((int)posO[b * NGT + jstar]);
    out[OFF_SC + (size_t)i * NC + lbl] = alignArr[i] * po / (pa + EPSF);
}

extern "C" void kernel_launch(void* const* d_in, const int* in_sizes, int n_in,
                              void* d_out, int out_size, void* d_ws, size_t ws_size,
                              hipStream_t stream) {
    const float* pd_scores = (const float*)d_in[0];
    const float* pd_bboxes = (const float*)d_in[1];
    const float* anc       = (const float*)d_in[2];
    const int*   gl_raw    = (const int*)d_in[3];
    const float* gt_bboxes = (const float*)d_in[4];
    const float* mask_gt   = (const float*)d_in[5];
    float* out = (float*)d_out;

    char* ws = (char*)d_ws;
    int*                flag     = (int*)(ws + WS_FLAG);
    int*                cnt      = (int*)(ws + WS_CNT);
    int*                minj     = (int*)(ws + WS_MINJ);
    int*                info     = (int*)(ws + WS_INFO);
    float*              alignArr = (float*)(ws + WS_ALIGN);
    unsigned int*       posA     = (unsigned int*)(ws + WS_POSA);
    unsigned int*       posO     = (unsigned int*)(ws + WS_POSO);
    int*                cnt2     = (int*)(ws + WS_CNT2);
    unsigned long long* cand     = (unsigned long long*)(ws + WS_CAND);

    k_init<<<8, 256, 0, stream>>>(posA, posO, cnt2, flag, gl_raw);
    k_cand<<<NCAND, 256, 0, stream>>>(pd_scores, pd_bboxes, anc, gl_raw,
                                      gt_bboxes, mask_gt, flag, cnt2, cand,
                                      cnt, minj, out);
    k_pick<<<BS * NGT / 4, 256, 0, stream>>>(cnt2, cand, cnt, minj);
    k_assign<<<(BS * A_N + 255) / 256, 256, 0, stream>>>(pd_scores, pd_bboxes, gt_bboxes,
                                                         gl_raw, flag, cnt, minj,
                                                         info, alignArr, posA, posO, out);
    k_norm<<<(BS * A_N + 255) / 256, 256, 0, stream>>>(info, alignArr, posA, posO, out);
}